// Round 1
// baseline (351.759 us; speedup 1.0000x reference)
//
#include <hip/hip_runtime.h>

// Segment-mean over N rows of F=256 f32 features into C=37 classes,
// scattered into queue[C][2][F] at slot tail[c].
//
// Pipeline:
//   k_accum : NB blocks, per-block LDS class sums (swizzled layout) -> partials in ws
//   k_reduce: (C x S) blocks, reduce NB partials -> S partials
//   k_final : C blocks, reduce S partials + counts, compute mean, scatter into queue

constexpr int C = 37;
constexpr int F = 256;

__global__ __launch_bounds__(256) void k_accum(
    const float* __restrict__ feat, const int* __restrict__ labels,
    float* __restrict__ psums, float* __restrict__ pcnts, int rpb)
{
    __shared__ float ls[C * F];
    __shared__ int   lc[C];
    const int tid = threadIdx.x;
    for (int i = tid; i < C * F; i += 256) ls[i] = 0.f;
    if (tid < C) lc[tid] = 0;
    __syncthreads();

    const int w    = tid >> 6;   // wave id 0..3
    const int lane = tid & 63;
    const size_t base = (size_t)blockIdx.x * (size_t)rpb;
    const float4* f4 = (const float4*)feat;
    const int iters = rpb >> 4;  // 16 rows per block-iteration (4 waves x 4 rows)

    for (int i = 0; i < iters; ++i) {
        const size_t r0 = base + (size_t)i * 16 + (size_t)w * 4;
        // 4 rows per wave, contiguous; 1 KB per global_load_dwordx4 per wave
        float4 v0 = f4[(r0 + 0) * 64 + lane];
        float4 v1 = f4[(r0 + 1) * 64 + lane];
        float4 v2 = f4[(r0 + 2) * 64 + lane];
        float4 v3 = f4[(r0 + 3) * 64 + lane];
        const int c0 = labels[r0 + 0];
        const int c1 = labels[r0 + 1];
        const int c2 = labels[r0 + 2];
        const int c3 = labels[r0 + 3];

        // Swizzled LDS layout: column (4*lane + j) of class c lives at
        // c*F + j*64 + lane  ->  bank = lane%32 per instruction: 2-way (free).
        const int p0 = c0 * F + lane;
        const int p1 = c1 * F + lane;
        const int p2 = c2 * F + lane;
        const int p3 = c3 * F + lane;
        __hip_atomic_fetch_add(&ls[p0      ], v0.x, __ATOMIC_RELAXED, __HIP_MEMORY_SCOPE_WORKGROUP);
        __hip_atomic_fetch_add(&ls[p0 +  64], v0.y, __ATOMIC_RELAXED, __HIP_MEMORY_SCOPE_WORKGROUP);
        __hip_atomic_fetch_add(&ls[p0 + 128], v0.z, __ATOMIC_RELAXED, __HIP_MEMORY_SCOPE_WORKGROUP);
        __hip_atomic_fetch_add(&ls[p0 + 192], v0.w, __ATOMIC_RELAXED, __HIP_MEMORY_SCOPE_WORKGROUP);
        __hip_atomic_fetch_add(&ls[p1      ], v1.x, __ATOMIC_RELAXED, __HIP_MEMORY_SCOPE_WORKGROUP);
        __hip_atomic_fetch_add(&ls[p1 +  64], v1.y, __ATOMIC_RELAXED, __HIP_MEMORY_SCOPE_WORKGROUP);
        __hip_atomic_fetch_add(&ls[p1 + 128], v1.z, __ATOMIC_RELAXED, __HIP_MEMORY_SCOPE_WORKGROUP);
        __hip_atomic_fetch_add(&ls[p1 + 192], v1.w, __ATOMIC_RELAXED, __HIP_MEMORY_SCOPE_WORKGROUP);
        __hip_atomic_fetch_add(&ls[p2      ], v2.x, __ATOMIC_RELAXED, __HIP_MEMORY_SCOPE_WORKGROUP);
        __hip_atomic_fetch_add(&ls[p2 +  64], v2.y, __ATOMIC_RELAXED, __HIP_MEMORY_SCOPE_WORKGROUP);
        __hip_atomic_fetch_add(&ls[p2 + 128], v2.z, __ATOMIC_RELAXED, __HIP_MEMORY_SCOPE_WORKGROUP);
        __hip_atomic_fetch_add(&ls[p2 + 192], v2.w, __ATOMIC_RELAXED, __HIP_MEMORY_SCOPE_WORKGROUP);
        __hip_atomic_fetch_add(&ls[p3      ], v3.x, __ATOMIC_RELAXED, __HIP_MEMORY_SCOPE_WORKGROUP);
        __hip_atomic_fetch_add(&ls[p3 +  64], v3.y, __ATOMIC_RELAXED, __HIP_MEMORY_SCOPE_WORKGROUP);
        __hip_atomic_fetch_add(&ls[p3 + 128], v3.z, __ATOMIC_RELAXED, __HIP_MEMORY_SCOPE_WORKGROUP);
        __hip_atomic_fetch_add(&ls[p3 + 192], v3.w, __ATOMIC_RELAXED, __HIP_MEMORY_SCOPE_WORKGROUP);
        if (lane == 0) {
            __hip_atomic_fetch_add(&lc[c0], 1, __ATOMIC_RELAXED, __HIP_MEMORY_SCOPE_WORKGROUP);
            __hip_atomic_fetch_add(&lc[c1], 1, __ATOMIC_RELAXED, __HIP_MEMORY_SCOPE_WORKGROUP);
            __hip_atomic_fetch_add(&lc[c2], 1, __ATOMIC_RELAXED, __HIP_MEMORY_SCOPE_WORKGROUP);
            __hip_atomic_fetch_add(&lc[c3], 1, __ATOMIC_RELAXED, __HIP_MEMORY_SCOPE_WORKGROUP);
        }
    }
    __syncthreads();

    // Un-swizzle and write this block's partials: thread t owns column t.
    float* po = psums + (size_t)blockIdx.x * (C * F);
    const int col = tid;
    const int sp  = (col & 3) * 64 + (col >> 2);   // swizzled position of column `col`
    for (int cc = 0; cc < C; ++cc) po[cc * F + col] = ls[cc * F + sp];
    if (tid < C) pcnts[(size_t)blockIdx.x * C + tid] = (float)lc[tid];
}

__global__ __launch_bounds__(256) void k_reduce(
    const float* __restrict__ psums, float* __restrict__ s2, int per_stripe)
{
    const int c = blockIdx.x;        // class
    const int s = blockIdx.y;        // stripe
    const int t = threadIdx.x;       // column
    const int b0 = s * per_stripe;
    float acc = 0.f;
    #pragma unroll 8
    for (int b = b0; b < b0 + per_stripe; ++b)
        acc += psums[((size_t)b * C + c) * F + t];
    s2[((size_t)s * C + c) * F + t] = acc;
}

__global__ __launch_bounds__(256) void k_final(
    const float* __restrict__ s2, const float* __restrict__ pcnts,
    const float* __restrict__ queue, const int* __restrict__ tail,
    float* __restrict__ out, int NB, int S)
{
    const int c = blockIdx.x;
    const int t = threadIdx.x;

    float s = 0.f;
    for (int k = 0; k < S; ++k) s += s2[((size_t)k * C + c) * F + t];

    // total count for class c: parallel partial sums + block tree-reduce
    __shared__ float red[256];
    float cnt = 0.f;
    for (int b = t; b < NB; b += 256) cnt += pcnts[(size_t)b * C + c];
    red[t] = cnt;
    __syncthreads();
    for (int off = 128; off > 0; off >>= 1) {
        if (t < off) red[t] += red[t + off];
        __syncthreads();
    }
    const float total = red[0];

    int tl = tail[c];
    tl = tl < 0 ? 0 : (tl > 1 ? 1 : tl);
    const bool  present = total > 0.f;
    const float mean    = s / fmaxf(total, 1.f);

    const float q0 = queue[((size_t)c * 2 + 0) * F + t];
    const float q1 = queue[((size_t)c * 2 + 1) * F + t];
    float o0 = q0, o1 = q1;
    if (tl == 0) o0 = present ? mean : q0;
    else         o1 = present ? mean : q1;
    out[((size_t)c * 2 + 0) * F + t] = o0;
    out[((size_t)c * 2 + 1) * F + t] = o1;
}

extern "C" void kernel_launch(void* const* d_in, const int* in_sizes, int n_in,
                              void* d_out, int out_size, void* d_ws, size_t ws_size,
                              hipStream_t stream)
{
    const float* feat   = (const float*)d_in[0];
    const int*   labels = (const int*)d_in[1];
    const float* queue  = (const float*)d_in[2];
    const int*   tail   = (const int*)d_in[3];
    float* out = (float*)d_out;
    float* ws  = (float*)d_ws;

    const int N = in_sizes[1];   // number of rows (N * F == in_sizes[0])
    const int S = 8;

    // Pick NB (power of two) so partials fit in the workspace. Deterministic:
    // depends only on ws_size.
    int NB = 512;
    while (NB > 32) {
        size_t need = ((size_t)NB * C * F + (size_t)NB * C + (size_t)S * C * F + 64) * sizeof(float);
        if (need <= ws_size) break;
        NB >>= 1;
    }
    const int rpb = N / NB;      // rows per block; N=2^18, NB=2^k -> divisible by 16

    float* psums = ws;
    float* pcnts = psums + (size_t)NB * C * F;
    float* s2    = pcnts + (size_t)NB * C;

    hipLaunchKernelGGL(k_accum,  dim3(NB),      dim3(256), 0, stream,
                       feat, labels, psums, pcnts, rpb);
    hipLaunchKernelGGL(k_reduce, dim3(C, S),    dim3(256), 0, stream,
                       psums, s2, NB / S);
    hipLaunchKernelGGL(k_final,  dim3(C),       dim3(256), 0, stream,
                       s2, pcnts, queue, tail, out, NB, S);
}

// Round 2
// 72.764 us; speedup vs baseline: 4.8342x; 4.8342x over previous
//
#include <hip/hip_runtime.h>

// Segment-mean over N rows of F=256 f32 features into C=37 classes,
// scattered into queue[C][2][F] at slot tail[c].
//
// k_accum: column-ownership accumulation — thread t exclusively owns feature
// column t; the whole block processes each (block-uniform) row, so the label
// load is scalar and LDS accumulation is plain read+add+write, NO atomics.
//
// Pipeline:
//   k_accum : NB blocks -> per-block class sums in ws
//   k_reduce: (C x S) blocks, reduce NB partials -> S partials
//   k_final : C blocks, reduce S partials + counts, compute mean, scatter

constexpr int C = 37;
constexpr int F = 256;

__global__ __launch_bounds__(256) void k_accum(
    const float* __restrict__ feat, const int* __restrict__ labels,
    float* __restrict__ psums, float* __restrict__ pcnts, int rpb)
{
    __shared__ float ls[C * F];
    const int t = threadIdx.x;
    for (int i = t; i < C * F; i += 256) ls[i] = 0.f;
    __syncthreads();

    const size_t base = (size_t)blockIdx.x * (size_t)rpb;
    int cnt = 0;  // count for class t (meaningful for t < C)

    // 8 rows per iteration: 8 independent coalesced loads in flight,
    // 8 scalar label loads (row index is block-uniform), 8 LDS RMW chains.
    for (int i = 0; i < rpb; i += 8) {
        const size_t r = base + (size_t)i;
        const float v0 = feat[(r + 0) * F + t];
        const float v1 = feat[(r + 1) * F + t];
        const float v2 = feat[(r + 2) * F + t];
        const float v3 = feat[(r + 3) * F + t];
        const float v4 = feat[(r + 4) * F + t];
        const float v5 = feat[(r + 5) * F + t];
        const float v6 = feat[(r + 6) * F + t];
        const float v7 = feat[(r + 7) * F + t];
        const int c0 = labels[r + 0];
        const int c1 = labels[r + 1];
        const int c2 = labels[r + 2];
        const int c3 = labels[r + 3];
        const int c4 = labels[r + 4];
        const int c5 = labels[r + 5];
        const int c6 = labels[r + 6];
        const int c7 = labels[r + 7];

        cnt += (c0 == t) + (c1 == t) + (c2 == t) + (c3 == t)
             + (c4 == t) + (c5 == t) + (c6 == t) + (c7 == t);

        // Thread t is the ONLY writer to column t of any class: race-free.
        // Sequential program order handles equal classes within the batch.
        ls[c0 * F + t] += v0;
        ls[c1 * F + t] += v1;
        ls[c2 * F + t] += v2;
        ls[c3 * F + t] += v3;
        ls[c4 * F + t] += v4;
        ls[c5 * F + t] += v5;
        ls[c6 * F + t] += v6;
        ls[c7 * F + t] += v7;
    }
    __syncthreads();

    float* po = psums + (size_t)blockIdx.x * (C * F);
    for (int cc = 0; cc < C; ++cc) po[cc * F + t] = ls[cc * F + t];
    if (t < C) pcnts[(size_t)blockIdx.x * C + t] = (float)cnt;
}

__global__ __launch_bounds__(256) void k_reduce(
    const float* __restrict__ psums, float* __restrict__ s2, int per_stripe)
{
    const int c = blockIdx.x;        // class
    const int s = blockIdx.y;        // stripe
    const int t = threadIdx.x;       // column
    const int b0 = s * per_stripe;
    float acc = 0.f;
    #pragma unroll 8
    for (int b = b0; b < b0 + per_stripe; ++b)
        acc += psums[((size_t)b * C + c) * F + t];
    s2[((size_t)s * C + c) * F + t] = acc;
}

__global__ __launch_bounds__(256) void k_final(
    const float* __restrict__ s2, const float* __restrict__ pcnts,
    const float* __restrict__ queue, const int* __restrict__ tail,
    float* __restrict__ out, int NB, int S)
{
    const int c = blockIdx.x;
    const int t = threadIdx.x;

    float s = 0.f;
    for (int k = 0; k < S; ++k) s += s2[((size_t)k * C + c) * F + t];

    __shared__ float red[256];
    float cnt = 0.f;
    for (int b = t; b < NB; b += 256) cnt += pcnts[(size_t)b * C + c];
    red[t] = cnt;
    __syncthreads();
    for (int off = 128; off > 0; off >>= 1) {
        if (t < off) red[t] += red[t + off];
        __syncthreads();
    }
    const float total = red[0];

    int tl = tail[c];
    tl = tl < 0 ? 0 : (tl > 1 ? 1 : tl);
    const bool  present = total > 0.f;
    const float mean    = s / fmaxf(total, 1.f);

    const float q0 = queue[((size_t)c * 2 + 0) * F + t];
    const float q1 = queue[((size_t)c * 2 + 1) * F + t];
    float o0 = q0, o1 = q1;
    if (tl == 0) o0 = present ? mean : q0;
    else         o1 = present ? mean : q1;
    out[((size_t)c * 2 + 0) * F + t] = o0;
    out[((size_t)c * 2 + 1) * F + t] = o1;
}

extern "C" void kernel_launch(void* const* d_in, const int* in_sizes, int n_in,
                              void* d_out, int out_size, void* d_ws, size_t ws_size,
                              hipStream_t stream)
{
    const float* feat   = (const float*)d_in[0];
    const int*   labels = (const int*)d_in[1];
    const float* queue  = (const float*)d_in[2];
    const int*   tail   = (const int*)d_in[3];
    float* out = (float*)d_out;
    float* ws  = (float*)d_ws;

    const int N = in_sizes[1];   // number of rows (N * F == in_sizes[0])
    const int S = 8;

    // Pick NB (power of two) so partials fit in the workspace.
    int NB = 512;
    while (NB > 32) {
        size_t need = ((size_t)NB * C * F + (size_t)NB * C + (size_t)S * C * F + 64) * sizeof(float);
        if (need <= ws_size) break;
        NB >>= 1;
    }
    const int rpb = N / NB;

    float* psums = ws;
    float* pcnts = psums + (size_t)NB * C * F;
    float* s2    = pcnts + (size_t)NB * C;

    hipLaunchKernelGGL(k_accum,  dim3(NB),   dim3(256), 0, stream,
                       feat, labels, psums, pcnts, rpb);
    hipLaunchKernelGGL(k_reduce, dim3(C, S), dim3(256), 0, stream,
                       psums, s2, NB / S);
    hipLaunchKernelGGL(k_final,  dim3(C),    dim3(256), 0, stream,
                       s2, pcnts, queue, tail, out, NB, S);
}

// Round 3
// 56.492 us; speedup vs baseline: 6.2268x; 1.2881x over previous
//
#include <hip/hip_runtime.h>

// Segment-mean over N rows of F=256 f32 features into C=37 classes,
// scattered into queue[C][2][F] at slot tail[c].
//
// k_accum: one row per WAVE via float4 (lane l owns cols [4l,4l+4)), each
// wave has a PRIVATE 37KB LDS class-sum buffer -> no cross-wave races, no
// atomics, 4x fewer load and LDS instructions than column-per-thread.
// Software-pipelined: next 8 rows are loaded into registers while the
// current 8 rows' LDS RMW chains run.

constexpr int C   = 37;
constexpr int F   = 256;
constexpr int WPB = 4;    // waves per block

__global__ __launch_bounds__(256) void k_accum(
    const float* __restrict__ feat, const int* __restrict__ labels,
    float* __restrict__ psums, float* __restrict__ pcnts, int rpw)
{
    __shared__ float ls[WPB][C * F];     // 4 x 37888 B = 148 KB
    __shared__ int   lcnt[WPB][64];
    const int t = threadIdx.x;
    const int w = t >> 6;
    const int l = t & 63;

    // Each wave zeroes its own buffer (no sync needed before use).
    float4* lz = (float4*)ls[w];
    for (int i = l; i < C * F / 4; i += 64)
        lz[i] = make_float4(0.f, 0.f, 0.f, 0.f);

    const size_t rbase = (size_t)blockIdx.x * (size_t)(rpw * WPB) + (size_t)w * rpw;
    const float4* f4 = (const float4*)feat;      // row r -> f4[r*64 + l]

    int cnt = 0;   // count for class l (meaningful for l < C)

    float4 buf[8]; int cls[8];
    #pragma unroll
    for (int k = 0; k < 8; ++k) {
        buf[k] = f4[(rbase + k) * 64 + l];
        cls[k] = labels[rbase + k];
    }

    for (int i = 0; i < rpw; i += 8) {
        float4 nbuf[8]; int ncls[8];
        const bool more = (i + 8) < rpw;     // wave-uniform branch
        if (more) {
            #pragma unroll
            for (int k = 0; k < 8; ++k) {
                nbuf[k] = f4[(rbase + i + 8 + k) * 64 + l];
                ncls[k] = labels[rbase + i + 8 + k];
            }
        }
        #pragma unroll
        for (int k = 0; k < 8; ++k) {
            const int c = cls[k];
            cnt += (c == l);
            float4* p = (float4*)&ls[w][c * F + 4 * l];  // lane-exclusive slot
            float4 a = *p;
            a.x += buf[k].x; a.y += buf[k].y; a.z += buf[k].z; a.w += buf[k].w;
            *p = a;
        }
        if (more) {
            #pragma unroll
            for (int k = 0; k < 8; ++k) { buf[k] = nbuf[k]; cls[k] = ncls[k]; }
        }
    }

    lcnt[w][l] = cnt;
    __syncthreads();

    // Reduce the 4 wave buffers, write this block's partial sums (37 KB).
    float* po = psums + (size_t)blockIdx.x * (C * F);
    for (int i = t; i < C * F; i += 256)
        po[i] = ls[0][i] + ls[1][i] + ls[2][i] + ls[3][i];
    if (t < C)
        pcnts[(size_t)blockIdx.x * C + t] =
            (float)(lcnt[0][t] + lcnt[1][t] + lcnt[2][t] + lcnt[3][t]);
}

__global__ __launch_bounds__(256) void k_reduce(
    const float* __restrict__ psums, float* __restrict__ s2, int per_stripe)
{
    const int c = blockIdx.x;        // class
    const int s = blockIdx.y;        // stripe
    const int t = threadIdx.x;       // column
    const int b0 = s * per_stripe;
    float acc = 0.f;
    #pragma unroll 8
    for (int b = b0; b < b0 + per_stripe; ++b)
        acc += psums[((size_t)b * C + c) * F + t];
    s2[((size_t)s * C + c) * F + t] = acc;
}

__global__ __launch_bounds__(256) void k_final(
    const float* __restrict__ s2, const float* __restrict__ pcnts,
    const float* __restrict__ queue, const int* __restrict__ tail,
    float* __restrict__ out, int NB, int S)
{
    const int c = blockIdx.x;
    const int t = threadIdx.x;

    float s = 0.f;
    for (int k = 0; k < S; ++k) s += s2[((size_t)k * C + c) * F + t];

    __shared__ float red[256];
    float cnt = 0.f;
    for (int b = t; b < NB; b += 256) cnt += pcnts[(size_t)b * C + c];
    red[t] = cnt;
    __syncthreads();
    for (int off = 128; off > 0; off >>= 1) {
        if (t < off) red[t] += red[t + off];
        __syncthreads();
    }
    const float total = red[0];

    int tl = tail[c];
    tl = tl < 0 ? 0 : (tl > 1 ? 1 : tl);
    const bool  present = total > 0.f;
    const float mean    = s / fmaxf(total, 1.f);

    const float q0 = queue[((size_t)c * 2 + 0) * F + t];
    const float q1 = queue[((size_t)c * 2 + 1) * F + t];
    float o0 = q0, o1 = q1;
    if (tl == 0) o0 = present ? mean : q0;
    else         o1 = present ? mean : q1;
    out[((size_t)c * 2 + 0) * F + t] = o0;
    out[((size_t)c * 2 + 1) * F + t] = o1;
}

extern "C" void kernel_launch(void* const* d_in, const int* in_sizes, int n_in,
                              void* d_out, int out_size, void* d_ws, size_t ws_size,
                              hipStream_t stream)
{
    const float* feat   = (const float*)d_in[0];
    const int*   labels = (const int*)d_in[1];
    const float* queue  = (const float*)d_in[2];
    const int*   tail   = (const int*)d_in[3];
    float* out = (float*)d_out;
    float* ws  = (float*)d_ws;

    const int N = in_sizes[1];   // number of rows
    const int S = 8;

    // NB = number of accum blocks (power of two), sized to fit workspace.
    int NB = 256;
    while (NB > 32) {
        size_t need = ((size_t)NB * C * F + (size_t)NB * C + (size_t)S * C * F + 64) * sizeof(float);
        if (need <= ws_size) break;
        NB >>= 1;
    }
    const int rpw = N / (NB * WPB);   // rows per wave

    float* psums = ws;
    float* pcnts = psums + (size_t)NB * C * F;
    float* s2    = pcnts + (size_t)NB * C;

    hipLaunchKernelGGL(k_accum,  dim3(NB),   dim3(256), 0, stream,
                       feat, labels, psums, pcnts, rpw);
    hipLaunchKernelGGL(k_reduce, dim3(C, S), dim3(256), 0, stream,
                       psums, s2, NB / S);
    hipLaunchKernelGGL(k_final,  dim3(C),    dim3(256), 0, stream,
                       s2, pcnts, queue, tail, out, NB, S);
}